// Round 2
// baseline (41657.950 us; speedup 1.0000x reference)
//
#include <hip/hip_runtime.h>
#include <math.h>

// Seq2Seq persistent cooperative kernel. 256 blocks x 512 threads (1 block/CU,
// 2 waves/SIMD). ~650 grid-syncs via hand-rolled epoch barrier replace ~650
// kernel launches. c-state lives in registers across all timesteps.

#define NBLK 256
#define NTHR 512
#define SEQ  200
#define TST  150
#define HID  512
#define G4   2048
#define VOC  231
#define EMBD 256
#define NB   256
#define BVO  (NB*VOC)   // 59136

__device__ __forceinline__ float sigf(float x) { return 1.0f / (1.0f + expf(-x)); }

// ---- epoch grid barrier: arrive slots (64B apart) + block0 aggregate + release ----
__device__ __forceinline__ void gsync(int* bar, int e) {
  __syncthreads();
  if (threadIdx.x == 0) {
    __threadfence();
    __hip_atomic_store(&bar[blockIdx.x * 16], e, __ATOMIC_RELEASE, __HIP_MEMORY_SCOPE_AGENT);
  }
  if (blockIdx.x == 0) {
    if (threadIdx.x < NBLK) {
      while (__hip_atomic_load(&bar[threadIdx.x * 16], __ATOMIC_ACQUIRE,
                               __HIP_MEMORY_SCOPE_AGENT) < e) {}
    }
    __syncthreads();
    if (threadIdx.x == 0)
      __hip_atomic_store(&bar[NBLK*16 + 16], e, __ATOMIC_RELEASE, __HIP_MEMORY_SCOPE_AGENT);
  }
  if (threadIdx.x == 0) {
    while (__hip_atomic_load(&bar[NBLK*16 + 16], __ATOMIC_ACQUIRE,
                             __HIP_MEMORY_SCOPE_AGENT) < e) {}
  }
  __syncthreads();
}

// ---- decoder X: GH = dWhh.h (2048 rows) and o1 = relu(W1.h + b1) (512 rows) ----
// WG: 20 rows x 128 cols. waves: q=K-quarter(4) x wc2=col-half(2). lane = 1 col.
__device__ __forceinline__ void phaseX(const float* __restrict__ hin,
    float* __restrict__ GHT, float* __restrict__ o1T,
    const float* __restrict__ dWhh, const float* __restrict__ W1,
    const float* __restrict__ b1, float* p)
{
  int tid = threadIdx.x, bid = blockIdx.x;
  int rg = bid >> 1, ch = bid & 1;
  int wv = tid >> 6, lane = tid & 63;
  int q = wv & 3, wc2 = wv >> 2;
  int cm = 64*wc2 + lane;
  int gb = 128*ch + cm;
  const float* wr[20];
#pragma unroll
  for (int r = 0; r < 20; ++r) {
    int j = 20*rg + r;
    wr[r] = (j < G4) ? (dWhh + (size_t)j*HID) : (W1 + (size_t)(j - G4)*HID);
  }
  float acc[20];
#pragma unroll
  for (int r = 0; r < 20; ++r) acc[r] = 0.f;
  const int k0 = q * 128;
#pragma unroll 4
  for (int kk = 0; kk < 128; ++kk) {
    float hv = hin[(size_t)(k0 + kk)*256 + gb];
#pragma unroll
    for (int r = 0; r < 20; ++r) acc[r] += wr[r][k0 + kk] * hv;
  }
#pragma unroll
  for (int r = 0; r < 20; ++r) p[(q*20 + r)*128 + cm] = acc[r];
  __syncthreads();
  int rr = tid >> 7, cc = tid & 127;
  int gbc = 128*ch + cc;
#pragma unroll
  for (int u = 0; u < 5; ++u) {
    int r = rr*5 + u;
    float s = p[(0*20 + r)*128 + cc] + p[(1*20 + r)*128 + cc]
            + p[(2*20 + r)*128 + cc] + p[(3*20 + r)*128 + cc];
    int j = 20*rg + r;
    if (j < G4) GHT[(size_t)j*256 + gbc] = s;
    else        o1T[(size_t)(j - G4)*256 + gbc] = fmaxf(s + b1[j - G4], 0.f);
  }
}

// ---- decoder Y: o2 = relu(W2.o1 + b2); write output row rout ----
// 116 active WGs: 8 rows x 64 cols, K-split 8 across waves.
__device__ __forceinline__ void phaseY(const float* __restrict__ o1T,
    float* __restrict__ o2T, const float* __restrict__ W2,
    const float* __restrict__ b2, float* __restrict__ out, int rout, float* p)
{
  int tid = threadIdx.x, bid = blockIdx.x;
  if (bid < 116) {
    int rg = bid >> 2, cg = bid & 3;
    int wv = tid >> 6, lane = tid & 63;
    int col = 64*cg + lane;
    const float* wr[8];
#pragma unroll
    for (int r = 0; r < 8; ++r) {
      int row = 8*rg + r; if (row > VOC-1) row = VOC-1;
      wr[r] = W2 + (size_t)row*HID;
    }
    float acc[8];
#pragma unroll
    for (int r = 0; r < 8; ++r) acc[r] = 0.f;
    const int k0 = wv * 64;
#pragma unroll 4
    for (int kk = 0; kk < 64; ++kk) {
      float v = o1T[(size_t)(k0 + kk)*256 + col];
#pragma unroll
      for (int r = 0; r < 8; ++r) acc[r] += wr[r][k0 + kk] * v;
    }
#pragma unroll
    for (int r = 0; r < 8; ++r) p[(wv*8 + r)*64 + lane] = acc[r];
    __syncthreads();
    int r = tid >> 6, c = tid & 63;
    int row = 8*rg + r, gc = 64*cg + c;
    if (row < VOC) {
      float s = 0.f;
#pragma unroll
      for (int q = 0; q < 8; ++q) s += p[(q*8 + r)*64 + c];
      s = fmaxf(s + b2[row], 0.f);
      o2T[(size_t)row*256 + gc] = s;
      out[(size_t)rout*BVO + (size_t)gc*VOC + row] = s;
    }
  }
}

// ---- decoder Z: argmax(o2[:,b]) -> tok; LSTM pointwise -> h_next[:,b] ----
__device__ __forceinline__ void phaseZ(const float* __restrict__ o2T,
    const float* __restrict__ GHT, const float* __restrict__ GIH,
    float* __restrict__ hout, float& cZ, int boot,
    const int* __restrict__ target, const float* __restrict__ cET,
    float* amv, int* ami)
{
  int tid = threadIdx.x, b = blockIdx.x;
  int tok;
  if (boot) {
    tok = target[b * TST];           // target[:,0]
    cZ  = cET[(size_t)tid*256 + b];  // encoder final c
  } else {
    if (tid < 256) {
      amv[tid] = (tid < VOC) ? o2T[(size_t)tid*256 + b] : -3.0e38f;
      ami[tid] = tid;
    }
    __syncthreads();
    for (int off = 128; off; off >>= 1) {
      if (tid < off) {
        float vo = amv[tid + off]; int io = ami[tid + off];
        if (vo > amv[tid] || (vo == amv[tid] && io < ami[tid])) {
          amv[tid] = vo; ami[tid] = io;
        }
      }
      __syncthreads();
    }
    tok = ami[0];
  }
  float pre[4];
#pragma unroll
  for (int g = 0; g < 4; ++g) {
    int gj = g*512 + tid;
    pre[g] = GHT[(size_t)gj*256 + b] + GIH[(size_t)tok*G4 + gj];
  }
  float ii = sigf(pre[0]), ff = sigf(pre[1]);
  float gg = tanhf(pre[2]), oo = sigf(pre[3]);
  cZ = ff * cZ + ii * gg;
  hout[(size_t)tid*256 + b] = oo * tanhf(cZ);
}

__global__ __launch_bounds__(NTHR, 1) void k_all(
    const float* __restrict__ train, const int* __restrict__ target,
    const float* __restrict__ fcW,  const float* __restrict__ fcb,
    const float* __restrict__ eWih, const float* __restrict__ eWhh,
    const float* __restrict__ ebih, const float* __restrict__ ebhh,
    const float* __restrict__ emb,  const float* __restrict__ dWih,
    const float* __restrict__ dWhh, const float* __restrict__ dbih,
    const float* __restrict__ dbhh, const float* __restrict__ W1,
    const float* __restrict__ b1,   const float* __restrict__ W2,
    const float* __restrict__ b2,   float* __restrict__ out,
    void* __restrict__ ws)
{
  __shared__ float p[10240];     // 40KB: enc 4x16x128 / X 4x20x128 / Y 8x8x64 / pre emb row
  __shared__ float amv[256];
  __shared__ int   ami[256];

  int* bar     = (int*)ws;              // 8192 ints (memset to 0 by host)
  float* fws   = (float*)ws + 8192;
  float* wcomb = fws;                   // 4096
  float* bcomb = wcomb + 4096;          // 2048
  float* GIH   = bcomb + 2048;          // 473088
  float* hTA   = GIH + 473088;          // 131072  [k][b]
  float* hTB   = hTA + 131072;          // 131072
  float* cET   = hTB + 131072;          // 131072
  float* o1T   = cET + 131072;          // 131072
  float* o2T   = o1T + 131072;          // 59136
  float* GHT   = o2T + 59136;           // 524288
  float* trainT= GHT + 524288;          // 102400  [t][f][b]

  int tid = threadIdx.x, bid = blockIdx.x;
  int ep = 1;

  // ================= pre-phase =================
  {
    int tg = bid * NTHR + tid;          // 0..131071
    hTA[tg] = 0.f;                      // h0 = 0
    if (tg < BVO) out[tg] = 0.f;        // outputs[0] = zeros
    if (tg < SEQ*2*NB) {                // transpose train -> [t][f][b]
      int t = tg >> 9, r = tg & 511, f = (tg >> 8) & 1, b = tg & 255;
      trainT[t*512 + f*256 + b] = train[((size_t)b*SEQ + t)*2 + f];
    }
    if (tg < G4) {                      // fold FC into enc input weights
      const float* wrow = eWih + (size_t)tg * EMBD;
      float s0 = 0.f, s1 = 0.f, sb = 0.f;
      for (int k = 0; k < EMBD; k += 4) {
        float4 w4 = *(const float4*)(wrow + k);
        s0 += w4.x*fcW[2*k]   + w4.y*fcW[2*k+2] + w4.z*fcW[2*k+4] + w4.w*fcW[2*k+6];
        s1 += w4.x*fcW[2*k+1] + w4.y*fcW[2*k+3] + w4.z*fcW[2*k+5] + w4.w*fcW[2*k+7];
        sb += w4.x*fcb[k]     + w4.y*fcb[k+1]   + w4.z*fcb[k+2]   + w4.w*fcb[k+3];
      }
      wcomb[2*tg]   = s0;
      wcomb[2*tg+1] = s1;
      bcomb[tg]     = sb + ebih[tg] + ebhh[tg];
    }
    __syncthreads();
    if (bid < VOC) {                    // GIH[v][j] = emb[v].dWih[j] + biases
      if (tid < EMBD) p[tid] = emb[(size_t)bid*EMBD + tid];
      __syncthreads();
      for (int u = 0; u < 4; ++u) {
        int j = u*512 + tid;
        const float* wrow = dWih + (size_t)j * EMBD;
        float s = 0.f;
        for (int k = 0; k < EMBD; k += 4) {
          float4 w4 = *(const float4*)(wrow + k);
          s += p[k]*w4.x + p[k+1]*w4.y + p[k+2]*w4.z + p[k+3]*w4.w;
        }
        GIH[(size_t)bid*G4 + j] = s + dbih[j] + dbhh[j];
      }
    }
  }
  gsync(bar, ep++);

  // ================= encoder: 200 steps =================
  {
    int kb = bid >> 1, ch = bid & 1;
    int wv = tid >> 6, lane = tid & 63;
    int q = wv & 3, wc2 = wv >> 2;
    int cm = 64*wc2 + lane;
    int gb_mm = 128*ch + cm;
    const float* ewr[16];
#pragma unroll
    for (int r = 0; r < 16; ++r)
      ewr[r] = eWhh + (size_t)((r >> 2)*512 + 4*kb + (r & 3)) * HID;
    int kq = tid >> 7, cp = tid & 127;
    int gb_pw = 128*ch + cp;
    int k_pw = 4*kb + kq;
    float cE = 0.f;
    const float* hin = hTA; float* hout = hTB;
    const int k0 = q * 128;
    for (int t = 0; t < SEQ; ++t) {
      float acc[16];
#pragma unroll
      for (int r = 0; r < 16; ++r) acc[r] = 0.f;
#pragma unroll 4
      for (int kk = 0; kk < 128; ++kk) {
        float hv = hin[(size_t)(k0 + kk)*256 + gb_mm];
#pragma unroll
        for (int r = 0; r < 16; ++r) acc[r] += ewr[r][k0 + kk] * hv;
      }
#pragma unroll
      for (int r = 0; r < 16; ++r) p[(q*16 + r)*128 + cm] = acc[r];
      __syncthreads();
      // pointwise (thread = (kq, col))
      float x0 = trainT[t*512 + gb_pw];
      float x1 = trainT[t*512 + 256 + gb_pw];
      float pre[4];
#pragma unroll
      for (int g = 0; g < 4; ++g) {
        float s = p[(0*16 + g*4 + kq)*128 + cp] + p[(1*16 + g*4 + kq)*128 + cp]
                + p[(2*16 + g*4 + kq)*128 + cp] + p[(3*16 + g*4 + kq)*128 + cp];
        int j = g*512 + k_pw;
        pre[g] = s + wcomb[2*j]*x0 + wcomb[2*j+1]*x1 + bcomb[j];
      }
      float ii = sigf(pre[0]), ff = sigf(pre[1]);
      float gg = tanhf(pre[2]), oo = sigf(pre[3]);
      cE = ff * cE + ii * gg;
      hout[(size_t)k_pw*256 + gb_pw] = oo * tanhf(cE);
      if (t == SEQ-1) cET[(size_t)k_pw*256 + gb_pw] = cE;
      const float* tmp = hin; hin = hout; hout = (float*)tmp;
      gsync(bar, ep++);
    }
  }
  // final encoder h is in hTA

  // ================= decoder =================
  float cZ = 0.f;
  // bootstrap: cell-0 with inp=target[:,0], h=h_enc, c=c_enc -> h_1 in hTB
  phaseX(hTA, GHT, o1T, dWhh, W1, b1, p);
  gsync(bar, ep++);
  phaseZ(o2T, GHT, GIH, hTB, cZ, 1, target, cET, amv, ami);
  gsync(bar, ep++);

  const float* cur = hTB; float* nxt = hTA;
  for (int s = 0; s < TST-1; ++s) {
    phaseX(cur, GHT, o1T, dWhh, W1, b1, p);   // GH(h_{s+1}), o1(h_{s+1})
    gsync(bar, ep++);
    phaseY(o1T, o2T, W2, b2, out, s + 1, p);  // out row s+1
    if (s == TST-2) break;                     // last output written; done
    gsync(bar, ep++);
    phaseZ(o2T, GHT, GIH, nxt, cZ, 0, target, cET, amv, ami);  // h_{s+2}
    gsync(bar, ep++);
    const float* tmp = cur; cur = nxt; nxt = (float*)tmp;
  }
}

extern "C" void kernel_launch(void* const* d_in, const int* in_sizes, int n_in,
                              void* d_out, int out_size, void* d_ws, size_t ws_size,
                              hipStream_t stream) {
  const float* train = (const float*)d_in[0];
  const int*   target= (const int*)  d_in[1];
  const float* fcW   = (const float*)d_in[2];
  const float* fcb   = (const float*)d_in[3];
  const float* eWih  = (const float*)d_in[4];
  const float* eWhh  = (const float*)d_in[5];
  const float* ebih  = (const float*)d_in[6];
  const float* ebhh  = (const float*)d_in[7];
  const float* emb   = (const float*)d_in[8];
  const float* dWih  = (const float*)d_in[9];
  const float* dWhh  = (const float*)d_in[10];
  const float* dbih  = (const float*)d_in[11];
  const float* dbhh  = (const float*)d_in[12];
  const float* W1    = (const float*)d_in[13];
  const float* b1    = (const float*)d_in[14];
  const float* W2    = (const float*)d_in[15];
  const float* b2    = (const float*)d_in[16];
  float* out = (float*)d_out;
  void* ws = d_ws;

  size_t need = (size_t)(8192 + 4096 + 2048 + 473088 + 4*131072 + 59136
                         + 524288 + 102400) * 4;
  if (ws_size < need) return;  // fail visibly

  hipMemsetAsync(d_ws, 0, 8192 * sizeof(int), stream);  // barrier slots

  void* args[] = { (void*)&train, (void*)&target, (void*)&fcW, (void*)&fcb,
                   (void*)&eWih, (void*)&eWhh, (void*)&ebih, (void*)&ebhh,
                   (void*)&emb, (void*)&dWih, (void*)&dWhh, (void*)&dbih,
                   (void*)&dbhh, (void*)&W1, (void*)&b1, (void*)&W2,
                   (void*)&b2, (void*)&out, (void*)&ws };
  hipError_t err = hipLaunchCooperativeKernel(
      reinterpret_cast<void*>(k_all), dim3(NBLK), dim3(NTHR), args, 0, stream);
  if (err != hipSuccess) {
    // fallback: plain launch. grid=256 blocks (>=1 resident per CU by
    // resource arithmetic: 42KB LDS, 512 thr, launch_bounds 512) -> barrier safe.
    k_all<<<dim3(NBLK), dim3(NTHR), 0, stream>>>(
        train, target, fcW, fcb, eWih, eWhh, ebih, ebhh, emb, dWih, dWhh,
        dbih, dbhh, W1, b1, W2, b2, out, ws);
  }
}

// Round 3
// 17407.269 us; speedup vs baseline: 2.3931x; 2.3931x over previous
//
#include <hip/hip_runtime.h>
#include <math.h>

// Persistent cooperative seq2seq, round 3.
// Key change vs r2: NO agent-scope fences in the per-epoch barrier (they
// invalidated the per-XCD L2 every sync -> 2.6GB HBM refetch, 41.7ms).
// Cross-block data moves via relaxed AGENT-scope atomics (per-instruction
// coherence at L3); weights stay normal cached loads, L2-resident.

#define NBLK 256
#define NTHR 512
#define SEQ  200
#define TST  150
#define HID  512
#define G4   2048
#define VOC  231
#define EMBD 256
#define NB   256
#define BVO  (NB*VOC)   // 59136

__device__ __forceinline__ float sigf(float x){ return 1.0f/(1.0f+expf(-x)); }

__device__ __forceinline__ float agld(const float* p){
  return __hip_atomic_load(p, __ATOMIC_RELAXED, __HIP_MEMORY_SCOPE_AGENT);
}
__device__ __forceinline__ void agst(float* p, float v){
  __hip_atomic_store(p, v, __ATOMIC_RELAXED, __HIP_MEMORY_SCOPE_AGENT);
}

// Light grid barrier: relaxed flags only. Ordering: __syncthreads drains each
// wave's vmcnt (relaxed-agent stores ack from coherence point) before arrival.
__device__ __forceinline__ void gsync(int* bar, int e) {
  __syncthreads();
  if (threadIdx.x == 0)
    __hip_atomic_store(&bar[16 + blockIdx.x*16], e, __ATOMIC_RELAXED, __HIP_MEMORY_SCOPE_AGENT);
  if (blockIdx.x == 0) {
    if (threadIdx.x < NBLK) {
      while (__hip_atomic_load(&bar[16 + threadIdx.x*16], __ATOMIC_RELAXED, __HIP_MEMORY_SCOPE_AGENT) < e)
        __builtin_amdgcn_s_sleep(1);
    }
    __syncthreads();
    if (threadIdx.x == 0)
      __hip_atomic_store(&bar[0], e, __ATOMIC_RELAXED, __HIP_MEMORY_SCOPE_AGENT);
  } else if (threadIdx.x == 0) {
    while (__hip_atomic_load(&bar[0], __ATOMIC_RELAXED, __HIP_MEMORY_SCOPE_AGENT) < e)
      __builtin_amdgcn_s_sleep(1);
  }
  __syncthreads();
}

// ---- encoder step: gates = eWhh@h (+folded input) + pointwise, c in register ----
// block: kb=bid>>1 (k-group of 4), ch=bid&1 (128-col half). 8 waves: q=K-quarter, wc2=col-64.
__device__ void encStep(const float* __restrict__ hin, float* __restrict__ hout,
    float* __restrict__ cET, const float* __restrict__ eWhh,
    const float* __restrict__ wcomb, const float* __restrict__ bcomb,
    const float* __restrict__ trainT, int t, int last, float& cE, float* p)
{
  int tid = threadIdx.x, bid = blockIdx.x;
  int kb = bid >> 1, ch = bid & 1;
  int wv = tid >> 6, lane = tid & 63;
  int q = wv & 3, wc2 = wv >> 2;
  int cm = 64*wc2 + lane;
  int gb = 128*ch + cm;
  const float* ewr[16];
#pragma unroll
  for (int r = 0; r < 16; ++r)
    ewr[r] = eWhh + (size_t)((r >> 2)*512 + 4*kb + (r & 3)) * HID;
  float acc[16];
#pragma unroll
  for (int r = 0; r < 16; ++r) acc[r] = 0.f;
  const int k0 = q * 128;
  float hv[8], hn[8];
#pragma unroll
  for (int u = 0; u < 8; ++u) hv[u] = agld(hin + (size_t)(k0+u)*256 + gb);
  for (int c8 = 0; c8 < 16; ++c8) {
    int kk = k0 + c8*8;
    if (c8 < 15) {
#pragma unroll
      for (int u = 0; u < 8; ++u) hn[u] = agld(hin + (size_t)(kk+8+u)*256 + gb);
    }
#pragma unroll
    for (int u = 0; u < 8; ++u) {
      float h = hv[u];
#pragma unroll
      for (int r = 0; r < 16; ++r) acc[r] += ewr[r][kk+u] * h;
    }
    if (c8 < 15) {
#pragma unroll
      for (int u = 0; u < 8; ++u) hv[u] = hn[u];
    }
  }
#pragma unroll
  for (int r = 0; r < 16; ++r) p[(q*16 + r)*128 + cm] = acc[r];
  __syncthreads();
  int kq = tid >> 7, cp = tid & 127;
  int gbp = 128*ch + cp;
  int k = 4*kb + kq;
  float x0 = trainT[t*512 + gbp];
  float x1 = trainT[t*512 + 256 + gbp];
  float pre[4];
#pragma unroll
  for (int g = 0; g < 4; ++g) {
    int r = g*4 + kq;
    float s = p[(0*16+r)*128+cp] + p[(1*16+r)*128+cp]
            + p[(2*16+r)*128+cp] + p[(3*16+r)*128+cp];
    int j = g*512 + k;
    pre[g] = s + wcomb[2*j]*x0 + wcomb[2*j+1]*x1 + bcomb[j];
  }
  float ii=sigf(pre[0]), ff=sigf(pre[1]), gg=tanhf(pre[2]), oo=sigf(pre[3]);
  cE = ff*cE + ii*gg;
  agst(hout + (size_t)k*256 + gbp, oo*tanhf(cE));
  if (last) agst(cET + (size_t)k*256 + gbp, cE);
}

// ---- decoder P: GH = dWhh@h (2048 rows, layout [b][j]) and o1 = relu(W1@h+b1) ([b][k]) ----
__device__ void phaseP(const float* __restrict__ hin, float* __restrict__ GHT,
    float* __restrict__ o1T, const float* __restrict__ dWhh,
    const float* __restrict__ W1, const float* __restrict__ b1, float* p)
{
  int tid = threadIdx.x, bid = blockIdx.x;
  int rg = bid >> 1, ch = bid & 1;
  int wv = tid >> 6, lane = tid & 63;
  int q = wv & 3, wc2 = wv >> 2;
  int cm = 64*wc2 + lane;
  int gb = 128*ch + cm;
  const float* wr[20];
#pragma unroll
  for (int r = 0; r < 20; ++r) {
    int j = 20*rg + r;
    wr[r] = (j < G4) ? (dWhh + (size_t)j*HID) : (W1 + (size_t)(j-G4)*HID);
  }
  float acc[20];
#pragma unroll
  for (int r = 0; r < 20; ++r) acc[r] = 0.f;
  const int k0 = q * 128;
  float hv[8], hn[8];
#pragma unroll
  for (int u = 0; u < 8; ++u) hv[u] = agld(hin + (size_t)(k0+u)*256 + gb);
  for (int c8 = 0; c8 < 16; ++c8) {
    int kk = k0 + c8*8;
    if (c8 < 15) {
#pragma unroll
      for (int u = 0; u < 8; ++u) hn[u] = agld(hin + (size_t)(kk+8+u)*256 + gb);
    }
#pragma unroll
    for (int u = 0; u < 8; ++u) {
      float h = hv[u];
#pragma unroll
      for (int r = 0; r < 20; ++r) acc[r] += wr[r][kk+u] * h;
    }
    if (c8 < 15) {
#pragma unroll
      for (int u = 0; u < 8; ++u) hv[u] = hn[u];
    }
  }
#pragma unroll
  for (int r = 0; r < 20; ++r) p[(q*20 + r)*128 + cm] = acc[r];
  __syncthreads();
  int rr = tid >> 7, cc = tid & 127;
  int b = 128*ch + cc;
#pragma unroll
  for (int u = 0; u < 5; ++u) {
    int r = rr*5 + u;
    float s = p[(0*20+r)*128+cc] + p[(1*20+r)*128+cc]
            + p[(2*20+r)*128+cc] + p[(3*20+r)*128+cc];
    int j = 20*rg + r;
    if (j < G4) agst(GHT + (size_t)b*G4 + j, s);
    else        agst(o1T + (size_t)b*HID + (j-G4), fmaxf(s + b1[j-G4], 0.f));
  }
}

// ---- decoder Q (blocks 0..127, 2 batch cols each): o2+argmax+out, LSTM pointwise ----
__device__ void phaseQ(int i, const float* __restrict__ GHT,
    const float* __restrict__ o1T, const float* __restrict__ GIH,
    const float* __restrict__ W2, const float* __restrict__ b2,
    const int* __restrict__ target, const float* __restrict__ cET,
    float* __restrict__ hnxt, float* __restrict__ out,
    float& cA, float& cB,
    float* o1sA, float* o1sB, float* o2A, float* o2B, float* amv, int* ami)
{
  int tid = threadIdx.x, bid = blockIdx.x;
  if (bid >= 128) return;
  int bA = 2*bid, bB = bA + 1;
  int tokA, tokB;
  if (i == 0) {
    tokA = target[bA*TST];
    tokB = target[bB*TST];
    cA = agld(cET + (size_t)tid*256 + bA);
    cB = agld(cET + (size_t)tid*256 + bB);
  } else {
    o1sA[tid] = agld(o1T + (size_t)bA*HID + tid);
    o1sB[tid] = agld(o1T + (size_t)bB*HID + tid);
    __syncthreads();
    if (tid < 2*VOC) {
      int row = tid >> 1, half = tid & 1;
      const float4* w4 = (const float4*)(W2 + (size_t)row*HID + half*256);
      const float4* aA = (const float4*)(o1sA + half*256);
      const float4* aB = (const float4*)(o1sB + half*256);
      float sA = 0.f, sB = 0.f;
#pragma unroll 8
      for (int qq = 0; qq < 64; ++qq) {
        float4 w = w4[qq], a = aA[qq], bb = aB[qq];
        sA += w.x*a.x + w.y*a.y + w.z*a.z + w.w*a.w;
        sB += w.x*bb.x + w.y*bb.y + w.z*bb.z + w.w*bb.w;
      }
      sA += __shfl_xor(sA, 1);
      sB += __shfl_xor(sB, 1);
      if (half == 0) {
        o2A[row] = fmaxf(sA + b2[row], 0.f);
        o2B[row] = fmaxf(sB + b2[row], 0.f);
      }
    }
    __syncthreads();
    {
      int tt = tid & 255;
      int base = (tid < 256) ? 0 : 256;
      const float* o2s = (tid < 256) ? o2A : o2B;
      amv[base + tt] = (tt < VOC) ? o2s[tt] : -3.0e38f;
      ami[base + tt] = tt;
      __syncthreads();
      for (int off = 128; off; off >>= 1) {
        if (tt < off) {
          float vo = amv[base + tt + off]; int io = ami[base + tt + off];
          if (vo > amv[base + tt] || (vo == amv[base + tt] && io < ami[base + tt])) {
            amv[base + tt] = vo; ami[base + tt] = io;
          }
        }
        __syncthreads();
      }
    }
    tokA = ami[0]; tokB = ami[256];
    if (tid < VOC)
      agst(out + (size_t)i*BVO + (size_t)bA*VOC + tid, o2A[tid]);
    else if (tid >= 256 && tid < 256 + VOC)
      agst(out + (size_t)i*BVO + (size_t)bB*VOC + (tid-256), o2B[tid-256]);
    if (i == TST-1) return;   // last output written; no further state needed
  }
  float preA[4], preB[4];
#pragma unroll
  for (int g = 0; g < 4; ++g) {
    int j = g*512 + tid;
    preA[g] = agld(GHT + (size_t)bA*G4 + j) + GIH[(size_t)tokA*G4 + j];
    preB[g] = agld(GHT + (size_t)bB*G4 + j) + GIH[(size_t)tokB*G4 + j];
  }
  {
    float ii=sigf(preA[0]), ff=sigf(preA[1]), gg=tanhf(preA[2]), oo=sigf(preA[3]);
    cA = ff*cA + ii*gg;
    agst(hnxt + (size_t)tid*256 + bA, oo*tanhf(cA));
  }
  {
    float ii=sigf(preB[0]), ff=sigf(preB[1]), gg=tanhf(preB[2]), oo=sigf(preB[3]);
    cB = ff*cB + ii*gg;
    agst(hnxt + (size_t)tid*256 + bB, oo*tanhf(cB));
  }
}

__global__ __launch_bounds__(NTHR, 1) void k_all(
    const float* __restrict__ train, const int* __restrict__ target,
    const float* __restrict__ fcW,  const float* __restrict__ fcb,
    const float* __restrict__ eWih, const float* __restrict__ eWhh,
    const float* __restrict__ ebih, const float* __restrict__ ebhh,
    const float* __restrict__ emb,  const float* __restrict__ dWih,
    const float* __restrict__ dWhh, const float* __restrict__ dbih,
    const float* __restrict__ dbhh, const float* __restrict__ W1,
    const float* __restrict__ b1,   const float* __restrict__ W2,
    const float* __restrict__ b2,   float* __restrict__ out,
    void* __restrict__ ws)
{
  __shared__ float p[10240];           // enc 4x16x128 / P 4x20x128 / pre emb row
  __shared__ float o1sA[512], o1sB[512];
  __shared__ float o2A[VOC], o2B[VOC];
  __shared__ float amv[512];
  __shared__ int   ami[512];

  int* bar     = (int*)ws;              // 8192 ints, host-memset to 0
  float* fws   = (float*)ws + 8192;
  float* wcomb = fws;                   // 4096
  float* bcomb = wcomb + 4096;          // 2048
  float* GIH   = bcomb + 2048;          // 473088
  float* hTA   = GIH + 473088;          // 131072  [k][b]
  float* hTB   = hTA + 131072;          // 131072
  float* cET   = hTB + 131072;          // 131072
  float* o1T   = cET + 131072;          // 131072  [b][k]
  float* GHT   = o1T + 131072;          // 524288  [b][j]
  float* trainT= GHT + 524288;          // 102400  [t][f][b]

  int tid = threadIdx.x, bid = blockIdx.x;
  int ep = 1;

  // ================= pre-phase (all ws writes relaxed-agent) =================
  {
    int tg = bid * NTHR + tid;          // 0..131071
    agst(&hTA[tg], 0.f);
    if (tg < BVO) agst(&out[tg], 0.f);
    if (tg < SEQ*2*NB) {
      int t = tg >> 9, f = (tg >> 8) & 1, b = tg & 255;
      agst(&trainT[tg], train[((size_t)b*SEQ + t)*2 + f]);
    }
    if (tg < G4) {
      const float* wrow = eWih + (size_t)tg * EMBD;
      float s0=0.f, s1=0.f, sb=0.f;
      for (int k2 = 0; k2 < EMBD; k2 += 4) {
        float4 w4 = *(const float4*)(wrow + k2);
        s0 += w4.x*fcW[2*k2]   + w4.y*fcW[2*k2+2] + w4.z*fcW[2*k2+4] + w4.w*fcW[2*k2+6];
        s1 += w4.x*fcW[2*k2+1] + w4.y*fcW[2*k2+3] + w4.z*fcW[2*k2+5] + w4.w*fcW[2*k2+7];
        sb += w4.x*fcb[k2]     + w4.y*fcb[k2+1]   + w4.z*fcb[k2+2]   + w4.w*fcb[k2+3];
      }
      agst(&wcomb[2*tg], s0);
      agst(&wcomb[2*tg+1], s1);
      agst(&bcomb[tg], sb + ebih[tg] + ebhh[tg]);
    }
    __syncthreads();
    if (bid < VOC) {
      if (tid < EMBD) p[tid] = emb[(size_t)bid*EMBD + tid];
      __syncthreads();
      for (int u = 0; u < 4; ++u) {
        int j = u*512 + tid;
        const float* wrow = dWih + (size_t)j*EMBD;
        float s = 0.f;
        for (int k2 = 0; k2 < EMBD; k2 += 4) {
          float4 w4 = *(const float4*)(wrow + k2);
          s += p[k2]*w4.x + p[k2+1]*w4.y + p[k2+2]*w4.z + p[k2+3]*w4.w;
        }
        agst(&GIH[(size_t)bid*G4 + j], s + dbih[j] + dbhh[j]);
      }
    }
  }
  gsync(bar, ep); ep++;
  // one-time heavy acquire: invalidate L1/L2/K$ so ws tables are safely cacheable
  if (tid == 0) {
    (void)__hip_atomic_load(&bar[0], __ATOMIC_ACQUIRE, __HIP_MEMORY_SCOPE_AGENT);
    asm volatile("s_dcache_inv" ::: "memory");
  }
  __syncthreads();

  // ================= encoder: 200 steps =================
  {
    float cE = 0.f;
    const float* hin = hTA; float* hout = hTB;
    for (int t = 0; t < SEQ; ++t) {
      encStep(hin, hout, cET, eWhh, wcomb, bcomb, trainT, t, t == SEQ-1, cE, p);
      gsync(bar, ep); ep++;
      const float* tmp = hin; hin = hout; hout = (float*)tmp;
    }
  }
  // h_enc in hTA (t=199 odd wrote hTA)

  // ================= decoder =================
  float cA = 0.f, cB = 0.f;
  phaseP(hTA, GHT, o1T, dWhh, W1, b1, p);
  gsync(bar, ep); ep++;
  phaseQ(0, GHT, o1T, GIH, W2, b2, target, cET, hTB, out, cA, cB,
         o1sA, o1sB, o2A, o2B, amv, ami);
  gsync(bar, ep); ep++;
  for (int i = 1; i < TST; ++i) {
    const float* cur = (i & 1) ? hTB : hTA;
    float* nxt      = (i & 1) ? hTA : hTB;
    phaseP(cur, GHT, o1T, dWhh, W1, b1, p);
    gsync(bar, ep); ep++;
    phaseQ(i, GHT, o1T, GIH, W2, b2, target, cET, nxt, out, cA, cB,
           o1sA, o1sB, o2A, o2B, amv, ami);
    gsync(bar, ep); ep++;
  }
}

extern "C" void kernel_launch(void* const* d_in, const int* in_sizes, int n_in,
                              void* d_out, int out_size, void* d_ws, size_t ws_size,
                              hipStream_t stream) {
  const float* train = (const float*)d_in[0];
  const int*   target= (const int*)  d_in[1];
  const float* fcW   = (const float*)d_in[2];
  const float* fcb   = (const float*)d_in[3];
  const float* eWih  = (const float*)d_in[4];
  const float* eWhh  = (const float*)d_in[5];
  const float* ebih  = (const float*)d_in[6];
  const float* ebhh  = (const float*)d_in[7];
  const float* emb   = (const float*)d_in[8];
  const float* dWih  = (const float*)d_in[9];
  const float* dWhh  = (const float*)d_in[10];
  const float* dbih  = (const float*)d_in[11];
  const float* dbhh  = (const float*)d_in[12];
  const float* W1    = (const float*)d_in[13];
  const float* b1    = (const float*)d_in[14];
  const float* W2    = (const float*)d_in[15];
  const float* b2    = (const float*)d_in[16];
  float* out = (float*)d_out;
  void* ws = d_ws;

  size_t need = (size_t)8192*4
              + (size_t)(4096 + 2048 + 473088 + 4*131072 + 524288 + 102400)*4;
  if (ws_size < need) return;  // fail visibly

  hipMemsetAsync(d_ws, 0, 8192 * sizeof(int), stream);  // barrier slots

  void* args[] = { (void*)&train, (void*)&target, (void*)&fcW, (void*)&fcb,
                   (void*)&eWih, (void*)&eWhh, (void*)&ebih, (void*)&ebhh,
                   (void*)&emb, (void*)&dWih, (void*)&dWhh, (void*)&dbih,
                   (void*)&dbhh, (void*)&W1, (void*)&b1, (void*)&W2,
                   (void*)&b2, (void*)&out, (void*)&ws };
  hipError_t err = hipLaunchCooperativeKernel(
      reinterpret_cast<void*>(k_all), dim3(NBLK), dim3(NTHR), args, 0, stream);
  if (err != hipSuccess) {
    // fallback: plain launch; grid=256 blocks at 1 block/CU -> all co-resident.
    k_all<<<dim3(NBLK), dim3(NTHR), 0, stream>>>(
        train, target, fcW, fcb, eWih, eWhh, ebih, ebhh, emb, dWih, dWhh,
        dbih, dbhh, W1, b1, W2, b2, out, ws);
  }
}